// Round 6
// baseline (325.471 us; speedup 1.0000x reference)
//
#include <hip/hip_runtime.h>

// ---- problem constants (from reference) ----
#define TSTEPS 256
#define NPOP 4
#define NI 8
#define NO 4
#define NF 28            // NI + 2*NR + NO
#define RANDN 512
#define NBATCH 64
#define NSTATES (NPOP*RANDN)   // 2048
#define THREADS 512            // waves 0-3 = main (recurrence), 4-7 = helper (base+y)
#define SPT 8                  // states per thread (256 "slots" x 8 = 2048)
#define ALPHA 0.2f             // DT/TAU
#define ONEMA 0.8f
#define HSTRIDE 12             // padded float stride for 8-float LDS records (bank spread)

__device__ __forceinline__ float vexp2(float x) { return __builtin_amdgcn_exp2f(x); }
__device__ __forceinline__ float vrcp(float x)  { return __builtin_amdgcn_rcpf(x); }

// tanh(x) = 1 - 2/(e^{2x}+1)
__device__ __forceinline__ float ftanh(float x) {
    float t = vexp2(x * 2.885390081777927f);
    return __builtin_fmaf(-2.0f, vrcp(t + 1.0f), 1.0f);
}

template<int CTRL, int RM, int BM>
__device__ __forceinline__ float dpp_add(float x) {
    int v = __builtin_amdgcn_update_dpp(0, __float_as_int(x), CTRL, RM, BM, true);
    return x + __int_as_float(v);
}

// full wave64 sum -> valid in lane 63
__device__ __forceinline__ float wave_red_sum(float x) {
    x = dpp_add<0x111, 0xf, 0xf>(x);
    x = dpp_add<0x112, 0xf, 0xf>(x);
    x = dpp_add<0x114, 0xf, 0xf>(x);
    x = dpp_add<0x118, 0xf, 0xf>(x);
    x = dpp_add<0x142, 0xa, 0xf>(x);
    x = dpp_add<0x143, 0xc, 0xf>(x);
    return x;
}

// sum within each 4-lane group -> valid at lanes 4g+3
__device__ __forceinline__ float red4(float x) {
    x = dpp_add<0x111, 0xf, 0xf>(x);
    x = dpp_add<0x112, 0xf, 0xf>(x);
    return x;
}

// barrier with LDS-only ordering (vmcnt stays in flight)
__device__ __forceinline__ void lds_barrier() {
    asm volatile("s_waitcnt lgkmcnt(0)\n\ts_barrier" ::: "memory");
}

__device__ __forceinline__ float readlane_f(float x, int l) {
    return __uint_as_float(__builtin_amdgcn_readlane(__float_as_uint(x), l));
}

__global__ __launch_bounds__(THREADS, 2)
void rnn_fused(
    const float* __restrict__ u,      // [B][T][NI]
    const float* __restrict__ G,      // [NPOP]
    const float* __restrict__ mu,     // [NPOP][NF]
    const float* __restrict__ C,      // [NPOP][NF][NF]
    const float* __restrict__ h0,     // [NPOP][RANDN]
    const float* __restrict__ nl,     // [NPOP][RANDN][NF]
    const float* __restrict__ nrec,   // [B][T][NPOP][RANDN]
    float* __restrict__ y)            // [B][T+1][NO]
{
    __shared__ float u_lds[TSTEPS * NI];                    // 8 KB (helpers read)
    __shared__ float c_lds[NPOP * NF * NF];                 // 12.25 KB
    __shared__ float mu_lds[NPOP * NF];
    __shared__ __align__(16) float h_lds[256 * HSTRIDE];    // 12 KB, main -> helper
    __shared__ __align__(16) float base_lds[256 * HSTRIDE]; // 12 KB, helper -> main
    __shared__ __align__(16) float part[2][4][8];           // kappa partials (main waves)
    __shared__ __align__(16) float ybuf[TSTEPS + 1][4][4];  // y partials (helper waves)

    const int tid  = threadIdx.x;
    const int b    = blockIdx.x;
    const int lane = tid & 63;
    const int wid  = tid >> 6;
    const bool is_main = (wid < 4);
    const int m    = is_main ? tid : (tid - 256);   // mirror slot 0..255
    const int p    = m >> 6;                         // population
    const int s0   = m * SPT;                        // first global state index

    // ---- stage u[b] into LDS (512 float4) ----
    {
        const float4* src = (const float4*)(u + (size_t)b * TSTEPS * NI);
        ((float4*)u_lds)[tid] = src[tid];
    }
    // ---- stage C into LDS (784 float4) ----
    {
        const float4* src = (const float4*)C;
        float4* dst = (float4*)c_lds;
        #pragma unroll
        for (int i = 0; i < 2; ++i) {
            int idx = tid + i * THREADS;
            if (idx < NPOP * NF * NF / 4) dst[idx] = src[idx];
        }
    }
    if (tid < NPOP * NF) mu_lds[tid] = mu[tid];

    // ---- softmax(G)/RANDN for this slot's population ----
    float w_p;
    {
        float g0 = G[0], g1 = G[1], g2 = G[2], g3 = G[3];
        float mx = fmaxf(fmaxf(g0, g1), fmaxf(g2, g3));
        const float L2E = 1.4426950408889634f;
        float e0 = vexp2((g0 - mx) * L2E), e1 = vexp2((g1 - mx) * L2E);
        float e2 = vexp2((g2 - mx) * L2E), e3 = vexp2((g3 - mx) * L2E);
        float inv = vrcp(e0 + e1 + e2 + e3);
        float ap = (p == 0) ? e0 : (p == 1) ? e1 : (p == 2) ? e2 : e3;
        w_p = ap * inv * (1.0f / (float)RANDN);
    }
    __syncthreads();   // staging + (below) h0 publish ordering handled by second sync

    const int s2addr = ((lane & 3) << 3) | (lane >> 3);
    float* yout = y + (size_t)b * (TSTEPS + 1) * NO;

    if (is_main) {
        // ============================ MAIN WAVES ============================
        // W[k][c]: c 0..7 = alpha*U (f=8..15), c 8..15 = w*V (f=16..23)
        float W[SPT][16];
        #pragma unroll
        for (int c = 0; c < 16; ++c) {
            float mm = mu_lds[p * NF + 8 + c];
            #pragma unroll
            for (int k = 0; k < SPT; ++k) W[k][c] = mm;
        }
        #pragma unroll
        for (int pr = 0; pr < 4; ++pr) {      // 2 states at a time
            float nlr[2][NF];
            #pragma unroll
            for (int kk = 0; kk < 2; ++kk) {
                const float4* src = (const float4*)(nl + (size_t)(s0 + pr * 2 + kk) * NF);
                #pragma unroll
                for (int q = 0; q < 7; ++q) {
                    float4 v = src[q];
                    nlr[kk][q*4+0] = v.x; nlr[kk][q*4+1] = v.y;
                    nlr[kk][q*4+2] = v.z; nlr[kk][q*4+3] = v.w;
                }
            }
            #pragma unroll
            for (int c = 0; c < 16; ++c) {
                const float4* cr = (const float4*)&c_lds[(p * NF + 8 + c) * NF];
                float crow[NF];
                #pragma unroll
                for (int q = 0; q < 7; ++q) {
                    float4 v = cr[q];
                    crow[q*4+0] = v.x; crow[q*4+1] = v.y;
                    crow[q*4+2] = v.z; crow[q*4+3] = v.w;
                }
                #pragma unroll
                for (int kk = 0; kk < 2; ++kk) {
                    float acc = W[pr*2+kk][c];
                    #pragma unroll
                    for (int ss = 0; ss < NF; ++ss)
                        acc = __builtin_fmaf(crow[ss], nlr[kk][ss], acc);
                    W[pr*2+kk][c] = acc;
                }
            }
        }
        #pragma unroll
        for (int k = 0; k < SPT; ++k) {
            #pragma unroll
            for (int c = 0; c < 8; ++c)  W[k][c] *= ALPHA;   // alpha*U
            #pragma unroll
            for (int c = 8; c < 16; ++c) W[k][c] *= w_p;     // w*V
        }

        // h init + publish h_0
        float h[SPT];
        {
            const float4* hp = (const float4*)(h0 + s0);
            float4 v0 = hp[0], v1 = hp[1];
            h[0]=v0.x; h[1]=v0.y; h[2]=v0.z; h[3]=v0.w;
            h[4]=v1.x; h[5]=v1.y; h[6]=v1.z; h[7]=v1.w;
        }
        {
            float4* hw = (float4*)&h_lds[m * HSTRIDE];
            hw[0] = float4{h[0], h[1], h[2], h[3]};
            hw[1] = float4{h[4], h[5], h[6], h[7]};
        }
        __syncthreads();   // h_0 + all staging visible

        for (int t = 0; t < TSTEPS; ++t) {
            // window 1: tanh + kappa partials + wave reduce
            float phi[SPT];
            #pragma unroll
            for (int k = 0; k < SPT; ++k) phi[k] = ftanh(h[k]);
            float red[8];
            #pragma unroll
            for (int r = 0; r < 8; ++r) {
                float a = phi[0] * W[0][8 + r];
                #pragma unroll
                for (int k = 1; k < SPT; ++k) a = __builtin_fmaf(phi[k], W[k][8 + r], a);
                red[r] = a;
            }
            #pragma unroll
            for (int r = 0; r < 8; ++r) red[r] = wave_red_sum(red[r]);
            if (lane == 63) {
                *(float4*)&part[t & 1][wid][0] = float4{red[0], red[1], red[2], red[3]};
                *(float4*)&part[t & 1][wid][4] = float4{red[4], red[5], red[6], red[7]};
            }
            lds_barrier();   // B2: part ready; helper's base_t ready

            // window 2 (serial-critical): stage2 + update + publish h
            __builtin_amdgcn_s_setprio(1);
            const float* pf = &part[t & 1][0][0];
            float pv = pf[s2addr];
            const float4* bp = (const float4*)&base_lds[m * HSTRIDE];
            float4 b0 = bp[0], b1 = bp[1];
            pv = red4(pv);
            float kf0 = readlane_f(pv, 3),  kf1 = readlane_f(pv, 11);
            float kf2 = readlane_f(pv, 19), kf3 = readlane_f(pv, 27);
            float kf4 = readlane_f(pv, 35), kf5 = readlane_f(pv, 43);
            float kf6 = readlane_f(pv, 51), kf7 = readlane_f(pv, 59);
            float bb[8] = {b0.x, b0.y, b0.z, b0.w, b1.x, b1.y, b1.z, b1.w};
            #pragma unroll
            for (int k = 0; k < SPT; ++k) {
                float r0 = kf0 * W[k][0];
                r0 = __builtin_fmaf(kf1, W[k][1], r0);
                r0 = __builtin_fmaf(kf2, W[k][2], r0);
                r0 = __builtin_fmaf(kf3, W[k][3], r0);
                float r1 = kf4 * W[k][4];
                r1 = __builtin_fmaf(kf5, W[k][5], r1);
                r1 = __builtin_fmaf(kf6, W[k][6], r1);
                r1 = __builtin_fmaf(kf7, W[k][7], r1);
                h[k] = bb[k] + (r0 + r1);
            }
            {
                float4* hw = (float4*)&h_lds[m * HSTRIDE];
                hw[0] = float4{h[0], h[1], h[2], h[3]};
                hw[1] = float4{h[4], h[5], h[6], h[7]};
            }
            __builtin_amdgcn_s_setprio(0);
            lds_barrier();   // B1: h_{t+1} published
        }
    } else {
        // =========================== HELPER WAVES ===========================
        // W[k][c]: c 0..7 = alpha*I (f=0..7), c 8..11 = w*O (f=24..27)
        float W[SPT][12];
        #pragma unroll
        for (int c = 0; c < 12; ++c) {
            int f = (c < 8) ? c : (16 + c);
            float mm = mu_lds[p * NF + f];
            #pragma unroll
            for (int k = 0; k < SPT; ++k) W[k][c] = mm;
        }
        #pragma unroll
        for (int pr = 0; pr < 4; ++pr) {
            float nlr[2][NF];
            #pragma unroll
            for (int kk = 0; kk < 2; ++kk) {
                const float4* src = (const float4*)(nl + (size_t)(s0 + pr * 2 + kk) * NF);
                #pragma unroll
                for (int q = 0; q < 7; ++q) {
                    float4 v = src[q];
                    nlr[kk][q*4+0] = v.x; nlr[kk][q*4+1] = v.y;
                    nlr[kk][q*4+2] = v.z; nlr[kk][q*4+3] = v.w;
                }
            }
            #pragma unroll
            for (int c = 0; c < 12; ++c) {
                int f = (c < 8) ? c : (16 + c);
                const float4* cr = (const float4*)&c_lds[(p * NF + f) * NF];
                float crow[NF];
                #pragma unroll
                for (int q = 0; q < 7; ++q) {
                    float4 v = cr[q];
                    crow[q*4+0] = v.x; crow[q*4+1] = v.y;
                    crow[q*4+2] = v.z; crow[q*4+3] = v.w;
                }
                #pragma unroll
                for (int kk = 0; kk < 2; ++kk) {
                    float acc = W[pr*2+kk][c];
                    #pragma unroll
                    for (int ss = 0; ss < NF; ++ss)
                        acc = __builtin_fmaf(crow[ss], nlr[kk][ss], acc);
                    W[pr*2+kk][c] = acc;
                }
            }
        }
        #pragma unroll
        for (int k = 0; k < SPT; ++k) {
            #pragma unroll
            for (int c = 0; c < 8; ++c)  W[k][c] *= ALPHA;   // alpha*I
            #pragma unroll
            for (int c = 8; c < 12; ++c) W[k][c] *= w_p;     // w*O
        }

        // noise prefetch (depth 2)
        const float4* nbase = (const float4*)nrec + (size_t)b * (TSTEPS * NSTATES / 4) + m * 2;
        float4 nA0 = nbase[0], nA1 = nbase[1];
        float4 nB0 = nbase[NSTATES / 4], nB1 = nbase[NSTATES / 4 + 1];
        __syncthreads();   // matches main's post-publish sync

        float hh[SPT];
        auto HSTEP = [&](int t, float4& nc0, float4& nc1) {
            // window 1: read h_t, compute base_t, publish
            {
                const float4* hp = (const float4*)&h_lds[m * HSTRIDE];
                float4 v0 = hp[0], v1 = hp[1];
                hh[0]=v0.x; hh[1]=v0.y; hh[2]=v0.z; hh[3]=v0.w;
                hh[4]=v1.x; hh[5]=v1.y; hh[6]=v1.z; hh[7]=v1.w;
            }
            float ut[8];
            {
                const float4* up = (const float4*)&u_lds[t * NI];
                float4 a = up[0], bb4 = up[1];
                ut[0]=a.x; ut[1]=a.y; ut[2]=a.z; ut[3]=a.w;
                ut[4]=bb4.x; ut[5]=bb4.y; ut[6]=bb4.z; ut[7]=bb4.w;
            }
            float nn[8] = {nc0.x, nc0.y, nc0.z, nc0.w, nc1.x, nc1.y, nc1.z, nc1.w};
            float base[SPT];
            #pragma unroll
            for (int k = 0; k < SPT; ++k) {
                float acc0 = ALPHA * nn[k];
                acc0 = __builtin_fmaf(ut[0], W[k][0], acc0);
                acc0 = __builtin_fmaf(ut[1], W[k][1], acc0);
                acc0 = __builtin_fmaf(ut[2], W[k][2], acc0);
                acc0 = __builtin_fmaf(ut[3], W[k][3], acc0);
                float acc1 = ut[4] * W[k][4];
                acc1 = __builtin_fmaf(ut[5], W[k][5], acc1);
                acc1 = __builtin_fmaf(ut[6], W[k][6], acc1);
                acc1 = __builtin_fmaf(ut[7], W[k][7], acc1);
                base[k] = __builtin_fmaf(ONEMA, hh[k], acc0 + acc1);
            }
            {
                float4* bw = (float4*)&base_lds[m * HSTRIDE];
                bw[0] = float4{base[0], base[1], base[2], base[3]};
                bw[1] = float4{base[4], base[5], base[6], base[7]};
            }
            // refill noise for t+2 (stays in flight across barriers)
            int tp = (t + 2 < TSTEPS) ? (t + 2) : (TSTEPS - 1);
            nc0 = nbase[(size_t)tp * (NSTATES / 4)];
            nc1 = nbase[(size_t)tp * (NSTATES / 4) + 1];
            lds_barrier();   // B2

            // window 2: y pipeline for step t (off the recurrence path)
            float phi[SPT];
            #pragma unroll
            for (int k = 0; k < SPT; ++k) phi[k] = ftanh(hh[k]);
            float yred[4];
            #pragma unroll
            for (int o = 0; o < 4; ++o) {
                float a = phi[0] * W[0][8 + o];
                #pragma unroll
                for (int k = 1; k < SPT; ++k) a = __builtin_fmaf(phi[k], W[k][8 + o], a);
                yred[o] = a;
            }
            #pragma unroll
            for (int o = 0; o < 4; ++o) yred[o] = wave_red_sum(yred[o]);
            if (lane == 63)
                *(float4*)&ybuf[t][wid - 4][0] = float4{yred[0], yred[1], yred[2], yred[3]};
            lds_barrier();   // B1
        };

        for (int t = 0; t < TSTEPS; t += 2) {
            HSTEP(t,     nA0, nA1);
            HSTEP(t + 1, nB0, nB1);
        }

        // final row y[T] from h_T (published by main's last window 2)
        {
            const float4* hp = (const float4*)&h_lds[m * HSTRIDE];
            float4 v0 = hp[0], v1 = hp[1];
            float phi[SPT] = {ftanh(v0.x), ftanh(v0.y), ftanh(v0.z), ftanh(v0.w),
                              ftanh(v1.x), ftanh(v1.y), ftanh(v1.z), ftanh(v1.w)};
            float yred[4];
            #pragma unroll
            for (int o = 0; o < 4; ++o) {
                float a = phi[0] * W[0][8 + o];
                #pragma unroll
                for (int k = 1; k < SPT; ++k) a = __builtin_fmaf(phi[k], W[k][8 + o], a);
                yred[o] = a;
            }
            #pragma unroll
            for (int o = 0; o < 4; ++o) yred[o] = wave_red_sum(yred[o]);
            if (lane == 63)
                *(float4*)&ybuf[TSTEPS][wid - 4][0] = float4{yred[0], yred[1], yred[2], yred[3]};
        }
    }

    lds_barrier();   // ybuf complete

    // ---- final y writeout: 1028 outputs, each sum of 4 helper-wave partials ----
    for (int idx = tid; idx < (TSTEPS + 1) * NO; idx += THREADS) {
        int t = idx >> 2, o = idx & 3;
        yout[idx] = (ybuf[t][0][o] + ybuf[t][1][o]) + (ybuf[t][2][o] + ybuf[t][3][o]);
    }
}

extern "C" void kernel_launch(void* const* d_in, const int* in_sizes, int n_in,
                              void* d_out, int out_size, void* d_ws, size_t ws_size,
                              hipStream_t stream) {
    const float* u    = (const float*)d_in[0];
    const float* G    = (const float*)d_in[1];
    const float* mu   = (const float*)d_in[2];
    const float* C    = (const float*)d_in[3];
    const float* h0   = (const float*)d_in[4];
    const float* nl   = (const float*)d_in[5];
    const float* nrec = (const float*)d_in[6];
    float* yp = (float*)d_out;

    rnn_fused<<<dim3(NBATCH), dim3(THREADS), 0, stream>>>(u, G, mu, C, h0, nl, nrec, yp);
}